// Round 4
// baseline (179.683 us; speedup 1.0000x reference)
//
#include <hip/hip_runtime.h>

// ForwardDistance: out[b,n,m] = sum_a agg[a] * tanh(datalin[b,n,a] + critlin[b,m,a])
// tanh(x+y) = 1 - 2/(1 + e^{2x} e^{2y})
// Phase 1 (proj_exp): barrier-free fp32 GEMM on vector ALU. 8 rows x 128 cols per
//   block; A-row loads are wave-broadcast, W rows coalesced 16B from L2. exp2
//   epilogue (clamp +-15 log2-units), LDS transpose, Ed^T/Ec^T [A][2048] -> ws.
// Phase 2 (tanh_reduce): 32x32 out tile per block, FULL a=256 per block ->
//   NO atomics, NO memset; 2 fma + 1 v_rcp per a-term; plain float2 stores.
//   (R2 lesson: atomics were the bottleneck — WRITE_SIZE == 4B x atomic count.)

#define A_DIM 256
#define K_DIM 512
#define NROWS 2048   // rows per source (B*N == B*M)

__global__ __launch_bounds__(256) void proj_exp_kernel(
    const float* __restrict__ data, const float* __restrict__ crit,
    const float* __restrict__ Wl, const float* __restrict__ bl,
    const float* __restrict__ Wr, const float* __restrict__ br,
    float* __restrict__ ws)
{
    __shared__ float es[128][12];    // [local col][row 0..7], pad 12 (16B-aligned rows)

    const int t   = threadIdx.x;
    const int bid = blockIdx.x;

    const int rowGroup = bid >> 1;           // 0..511
    const int colHalf  = bid & 1;
    const int r0  = rowGroup * 8;            // global row base 0..4088
    const int src = r0 >> 11;                // 0 = data, 1 = crit
    const int lr  = r0 & 2047;               // row base within source
    const int c0  = colHalf * 128;

    const float* X    = src ? crit : data;
    const float* W    = src ? Wr   : Wl;
    const float* bias = src ? br   : bl;
    float* ET = ws + (size_t)src * ((size_t)A_DIM * NROWS);

    const int ty = t >> 5;                   // row 0..7
    const int tx = t & 31;                   // col group (4 cols): 32x16B = 512B coalesced
    const int c  = c0 + tx * 4;
    const float* rowPtr = X + (size_t)(lr + ty) * K_DIM;
    const float* wp     = W + c;

    float acc0 = 0.f, acc1 = 0.f, acc2 = 0.f, acc3 = 0.f;
#pragma unroll 2
    for (int k0 = 0; k0 < K_DIM; k0 += 8) {
        float4 alo = *(const float4*)(rowPtr + k0);
        float4 ahi = *(const float4*)(rowPtr + k0 + 4);
        const float a8[8] = {alo.x, alo.y, alo.z, alo.w, ahi.x, ahi.y, ahi.z, ahi.w};
#pragma unroll
        for (int kk = 0; kk < 8; kk++) {
            float4 b4 = *(const float4*)(wp + (size_t)(k0 + kk) * A_DIM);
            acc0 = fmaf(a8[kk], b4.x, acc0);
            acc1 = fmaf(a8[kk], b4.y, acc1);
            acc2 = fmaf(a8[kk], b4.z, acc2);
            acc3 = fmaf(a8[kk], b4.w, acc3);
        }
    }

    // E = exp2( clamp( 2*log2(e)*(acc+bias), +-15 ) )  (clamp inactive for this data;
    // guarantees q = 1 + Ed*Ec <= 1 + 2^30 in phase 2 -> rcp exact-safe)
    const float c2 = 2.8853900817779268f;    // 2*log2(e)
    const float4 bv = *(const float4*)(bias + c);
    const float accs[4] = {acc0, acc1, acc2, acc3};
    const float bvv[4]  = {bv.x, bv.y, bv.z, bv.w};
#pragma unroll
    for (int j = 0; j < 4; j++) {
        float v = (accs[j] + bvv[j]) * c2;
        v = fminf(fmaxf(v, -15.f), 15.f);
        es[tx * 4 + j][ty] = __builtin_amdgcn_exp2f(v);
    }
    __syncthreads();
    // transpose out: lane -> (local col ap, row half h); 16B store to ET[a][row]
    {
        const int ap = t >> 1;               // 0..127
        const int h  = t & 1;                // rows h*4 .. h*4+3
        float4 v = *(const float4*)&es[ap][h * 4];
        *(float4*)(ET + (size_t)(c0 + ap) * NROWS + lr + h * 4) = v;
    }
}

__global__ __launch_bounds__(256) void tanh_reduce_kernel(
    const float* __restrict__ ws, const float* __restrict__ agg,
    float* __restrict__ out)
{
    __shared__ __align__(16) float et [64][34];   // [a][n]
    __shared__ __align__(16) float ect[64][34];   // [a][m]
    __shared__ float aggs[256];                   // 2*agg

    const int t   = threadIdx.x;
    const int bid = blockIdx.x;
    const int b   = bid >> 8;                // 0..3
    const int rem = bid & 255;
    const int n0  = (rem >> 4) * 32;
    const int m0  = (rem & 15) * 32;

    const float* EdT = ws;                           // [A][2048]
    const float* EcT = ws + (size_t)A_DIM * NROWS;   // [A][2048]
    const int row_n = b * 512 + n0;
    const int row_m = b * 512 + m0;

    const int tx = t & 15;                   // m pair
    const int ty = t >> 4;                   // n pair

    aggs[t] = 2.0f * agg[t];                 // synced by first barrier in the loop

    float acc00 = 0.f, acc01 = 0.f, acc10 = 0.f, acc11 = 0.f;
    float sagg = 0.f;

    for (int ch = 0; ch < 4; ch++) {
        const int a0 = ch * 64;
        __syncthreads();                     // previous chunk's LDS reads done
        // stage 64 a x 32 rows of each table: 8 lanes x 16B = 128B contiguous per a
#pragma unroll
        for (int rep = 0; rep < 2; rep++) {
            const int aL  = rep * 32 + (t >> 3);
            const int seg = (t & 7) * 4;
            *(float4*)&et [aL][seg] = *(const float4*)(EdT + (size_t)(a0 + aL) * NROWS + row_n + seg);
            *(float4*)&ect[aL][seg] = *(const float4*)(EcT + (size_t)(a0 + aL) * NROWS + row_m + seg);
        }
        __syncthreads();

        for (int aq = 0; aq < 16; aq++) {
            const float4 ag = *(const float4*)&aggs[a0 + aq * 4];
            sagg += (ag.x + ag.y) + (ag.z + ag.w);
            const float agv[4] = {ag.x, ag.y, ag.z, ag.w};
#pragma unroll
            for (int u = 0; u < 4; u++) {
                const int a = aq * 4 + u;
                const float2 e = *(const float2*)&et [a][ty * 2];  // broadcast within 16 lanes
                const float2 c = *(const float2*)&ect[a][tx * 2];  // conflict-free (16 addrs x b64)
                float q00 = fmaf(e.x, c.x, 1.0f);
                float q01 = fmaf(e.x, c.y, 1.0f);
                float q10 = fmaf(e.y, c.x, 1.0f);
                float q11 = fmaf(e.y, c.y, 1.0f);
                acc00 = fmaf(agv[u], __builtin_amdgcn_rcpf(q00), acc00);
                acc01 = fmaf(agv[u], __builtin_amdgcn_rcpf(q01), acc01);
                acc10 = fmaf(agv[u], __builtin_amdgcn_rcpf(q10), acc10);
                acc11 = fmaf(agv[u], __builtin_amdgcn_rcpf(q11), acc11);
            }
        }
    }

    // tanh = 1 - 2/q  =>  out = sum(agg) - sum(2agg/q);  sagg = 2*sum(agg)
    const float base = 0.5f * sagg;
    float2 r0v, r1v;
    r0v.x = base - acc00; r0v.y = base - acc01;
    r1v.x = base - acc10; r1v.y = base - acc11;
    float* o0 = out + ((size_t)(b * 512 + n0 + ty * 2) * 512) + m0 + tx * 2;
    *(float2*)o0         = r0v;
    *(float2*)(o0 + 512) = r1v;
}

extern "C" void kernel_launch(void* const* d_in, const int* in_sizes, int n_in,
                              void* d_out, int out_size, void* d_ws, size_t ws_size,
                              hipStream_t stream) {
    const float* data = (const float*)d_in[0];
    const float* crit = (const float*)d_in[1];
    const float* Wl   = (const float*)d_in[2];
    const float* bl   = (const float*)d_in[3];
    const float* Wr   = (const float*)d_in[4];
    const float* br   = (const float*)d_in[5];
    const float* agg  = (const float*)d_in[6];
    float* out = (float*)d_out;
    float* ws  = (float*)d_ws;   // 2 * 256 * 2048 * 4 B = 4 MB

    // Phase 1: 512 row-groups x 2 col-halves = 1024 blocks; barrier-free K-loop
    proj_exp_kernel<<<dim3(1024), 256, 0, stream>>>(data, crit, Wl, bl, Wr, br, ws);

    // Phase 2: (16 m-tiles x 16 n-tiles) x 4 batches = 1024 blocks; no atomics
    tanh_reduce_kernel<<<dim3(1024), 256, 0, stream>>>(ws, agg, out);
}

// Round 5
// 117.319 us; speedup vs baseline: 1.5316x; 1.5316x over previous
//
#include <hip/hip_runtime.h>

// ForwardDistance: out[b,n,m] = sum_a agg[a] * tanh(datalin[b,n,a] + critlin[b,m,a])
// tanh(x+y) = 1 - 2/(1 + e^{2x} e^{2y});  e^{2(p1+p2+b)} = E1 * E2 (K-split factors)
// Phase 1 (proj_exp): LDS-tiled fp32 GEMM, 64x64 tile, 4x4/thread, K split in two
//   256-halves across blocks (512 blocks = 2/CU). Each half stores a bf16 factor
//   E = exp2(clamp(2log2e*(partial[+bias]), +-15)) transposed [a][row] in ws.
//   (R4 lesson: per-wave W re-fetch = 2 GB L2 traffic = 24 TB/s = the 85 us.)
// Phase 2 (tanh_reduce): 32x32 out tile, full a=256, NO atomics. Staging multiplies
//   the two bf16 factors -> fp32 LDS. Inner: pair-grouped rcp (6 VALU + 1 v_rcp
//   per 2 a-terms); q <= 1+2^60, D = q0*q1 <= 2^121 < FLT_MAX. Plain float2 stores.

#define A_DIM 256
#define K_DIM 512
#define NROWS 2048   // rows per source (B*N == B*M)

typedef unsigned short ushort;
typedef __attribute__((ext_vector_type(4))) unsigned short us4;

__device__ inline ushort f2bf(float x) {    // round-to-nearest-even bf16
    union { float f; unsigned u; } v; v.f = x;
    unsigned r = v.u + 0x7FFFu + ((v.u >> 16) & 1u);
    return (ushort)(r >> 16);
}
__device__ inline float bf2f(ushort h) {
    union { unsigned u; float f; } v; v.u = ((unsigned)h) << 16; return v.f;
}

__global__ __launch_bounds__(256) void proj_exp_kernel(
    const float* __restrict__ data, const float* __restrict__ crit,
    const float* __restrict__ Wl, const float* __restrict__ bl,
    const float* __restrict__ Wr, const float* __restrict__ br,
    ushort* __restrict__ ws16)
{
    __shared__ __align__(16) float Xs[16][68];   // [k][row], pad 68 (16B-aligned rows)
    __shared__ __align__(16) float Wsm[16][64];  // [k][col]

    const int t   = threadIdx.x;
    const int bid = blockIdx.x;
    const int ct  = bid & 3;            // col tile (64 cols)
    const int rt  = (bid >> 2) & 31;    // row tile (64 rows)
    const int kh  = (bid >> 7) & 1;     // K half
    const int src = bid >> 8;           // 0 = data, 1 = crit

    const int r0 = rt * 64, c0 = ct * 64, kb = kh * 256;
    const float* X    = src ? crit : data;
    const float* W    = src ? Wr   : Wl;
    const float* bias = src ? br   : bl;
    ushort* ET = ws16 + (size_t)(src * 2 + kh) * ((size_t)A_DIM * NROWS);

    const int tx = t & 15;              // 4 cols
    const int ty = t >> 4;              // 4 rows
    const int sr = t >> 2;              // X staging: row 0..63
    const int sk = (t & 3) * 4;         //            k seg
    const int wk = t >> 4;              // W staging: k row 0..15
    const int wc = (t & 15) * 4;        //            col seg

    float acc[4][4];
#pragma unroll
    for (int i = 0; i < 4; i++)
#pragma unroll
        for (int j = 0; j < 4; j++) acc[i][j] = 0.f;

    for (int k0 = 0; k0 < 256; k0 += 16) {
        float4 xv = *(const float4*)(X + (size_t)(r0 + sr) * K_DIM + kb + k0 + sk);
        float4 wv = *(const float4*)(W + (size_t)(kb + k0 + wk) * A_DIM + c0 + wc);
        __syncthreads();                // previous chunk's LDS reads complete
        Xs[sk + 0][sr] = xv.x; Xs[sk + 1][sr] = xv.y;
        Xs[sk + 2][sr] = xv.z; Xs[sk + 3][sr] = xv.w;
        *(float4*)&Wsm[wk][wc] = wv;
        __syncthreads();
#pragma unroll
        for (int kk = 0; kk < 16; kk++) {
            float4 a4 = *(const float4*)&Xs[kk][ty * 4];
            float4 b4 = *(const float4*)&Wsm[kk][tx * 4];
            const float aa[4] = {a4.x, a4.y, a4.z, a4.w};
            const float bb[4] = {b4.x, b4.y, b4.z, b4.w};
#pragma unroll
            for (int i = 0; i < 4; i++)
#pragma unroll
                for (int j = 0; j < 4; j++)
                    acc[i][j] = fmaf(aa[i], bb[j], acc[i][j]);
        }
    }

    // factor: E = exp2( clamp( 2*log2(e)*(acc [+bias if kh==0]), +-15 ) )
    // clamp inactive for this data (|half-sum| > 5.2 is ~7 sigma); bounds q for rcp.
    const float c2 = 2.8853900817779268f;    // 2*log2(e)
    float bvv[4] = {0.f, 0.f, 0.f, 0.f};
    if (kh == 0) {
        float4 bv = *(const float4*)(bias + c0 + tx * 4);
        bvv[0] = bv.x; bvv[1] = bv.y; bvv[2] = bv.z; bvv[3] = bv.w;
    }
#pragma unroll
    for (int j = 0; j < 4; j++) {
        us4 ev;
#pragma unroll
        for (int i = 0; i < 4; i++) {
            float v = (acc[i][j] + bvv[j]) * c2;
            v = fminf(fmaxf(v, -15.f), 15.f);
            ev[i] = f2bf(__builtin_amdgcn_exp2f(v));
        }
        // rows r0+ty*4.. are contiguous in ET[a][row] -> 8B store
        *(us4*)(ET + (size_t)(c0 + tx * 4 + j) * NROWS + r0 + ty * 4) = ev;
    }
}

__global__ __launch_bounds__(256) void tanh_reduce_kernel(
    const ushort* __restrict__ ws16, const float* __restrict__ agg,
    float* __restrict__ out)
{
    __shared__ __align__(16) float et [64][34];   // [a][n] = E1d*E2d
    __shared__ __align__(16) float ect[64][34];   // [a][m] = E1c*E2c
    __shared__ float aggs[256];                   // 2*agg

    const int t   = threadIdx.x;
    const int bid = blockIdx.x;
    const int b   = bid >> 8;
    const int rem = bid & 255;
    const int n0  = (rem >> 4) * 32;
    const int m0  = (rem & 15) * 32;

    const size_t PLANE = (size_t)A_DIM * NROWS;
    const ushort* E1d = ws16;
    const ushort* E2d = ws16 + PLANE;
    const ushort* E1c = ws16 + 2 * PLANE;
    const ushort* E2c = ws16 + 3 * PLANE;
    const int row_n = b * 512 + n0;
    const int row_m = b * 512 + m0;

    const int tx = t & 15;                   // m pair
    const int ty = t >> 4;                   // n pair

    aggs[t] = 2.0f * agg[t];                 // covered by first barrier in loop

    float acc00 = 0.f, acc01 = 0.f, acc10 = 0.f, acc11 = 0.f;
    float sagg = 0.f;

    for (int ch = 0; ch < 4; ch++) {
        const int a0 = ch * 64;
        __syncthreads();                     // previous chunk's LDS reads done
#pragma unroll
        for (int rep = 0; rep < 2; rep++) {
            const int aL  = rep * 32 + (t >> 3);
            const int seg = (t & 7) * 4;
            const size_t offn = (size_t)(a0 + aL) * NROWS + row_n + seg;
            const size_t offm = (size_t)(a0 + aL) * NROWS + row_m + seg;
            us4 d1 = *(const us4*)(E1d + offn);
            us4 d2 = *(const us4*)(E2d + offn);
            us4 c1 = *(const us4*)(E1c + offm);
            us4 c2 = *(const us4*)(E2c + offm);
            float4 ev, cv;
            ev.x = bf2f(d1[0]) * bf2f(d2[0]); ev.y = bf2f(d1[1]) * bf2f(d2[1]);
            ev.z = bf2f(d1[2]) * bf2f(d2[2]); ev.w = bf2f(d1[3]) * bf2f(d2[3]);
            cv.x = bf2f(c1[0]) * bf2f(c2[0]); cv.y = bf2f(c1[1]) * bf2f(c2[1]);
            cv.z = bf2f(c1[2]) * bf2f(c2[2]); cv.w = bf2f(c1[3]) * bf2f(c2[3]);
            *(float4*)&et [aL][seg] = ev;
            *(float4*)&ect[aL][seg] = cv;
        }
        __syncthreads();

        for (int ap = 0; ap < 32; ap++) {    // a-pairs: one rcp per 2 a-terms
            const float2 ag = *(const float2*)&aggs[a0 + ap * 2];
            sagg += ag.x + ag.y;
            const float2 e0 = *(const float2*)&et [ap * 2 + 0][ty * 2];
            const float2 e1 = *(const float2*)&et [ap * 2 + 1][ty * 2];
            const float2 f0 = *(const float2*)&ect[ap * 2 + 0][tx * 2];
            const float2 f1 = *(const float2*)&ect[ap * 2 + 1][tx * 2];
            {   // (n=+0, m=+0)
                float q0 = fmaf(e0.x, f0.x, 1.f), q1 = fmaf(e1.x, f1.x, 1.f);
                acc00 = fmaf(fmaf(ag.x, q1, ag.y * q0), __builtin_amdgcn_rcpf(q0 * q1), acc00);
            }
            {   // (n=+0, m=+1)
                float q0 = fmaf(e0.x, f0.y, 1.f), q1 = fmaf(e1.x, f1.y, 1.f);
                acc01 = fmaf(fmaf(ag.x, q1, ag.y * q0), __builtin_amdgcn_rcpf(q0 * q1), acc01);
            }
            {   // (n=+1, m=+0)
                float q0 = fmaf(e0.y, f0.x, 1.f), q1 = fmaf(e1.y, f1.x, 1.f);
                acc10 = fmaf(fmaf(ag.x, q1, ag.y * q0), __builtin_amdgcn_rcpf(q0 * q1), acc10);
            }
            {   // (n=+1, m=+1)
                float q0 = fmaf(e0.y, f0.y, 1.f), q1 = fmaf(e1.y, f1.y, 1.f);
                acc11 = fmaf(fmaf(ag.x, q1, ag.y * q0), __builtin_amdgcn_rcpf(q0 * q1), acc11);
            }
        }
    }

    // tanh = 1 - 2/q  =>  out = sum(agg) - sum(2agg/q);  sagg = 2*sum(agg)
    const float base = 0.5f * sagg;
    float2 r0v, r1v;
    r0v.x = base - acc00; r0v.y = base - acc01;
    r1v.x = base - acc10; r1v.y = base - acc11;
    float* o0 = out + ((size_t)(b * 512 + n0 + ty * 2) * 512) + m0 + tx * 2;
    *(float2*)o0         = r0v;
    *(float2*)(o0 + 512) = r1v;
}

extern "C" void kernel_launch(void* const* d_in, const int* in_sizes, int n_in,
                              void* d_out, int out_size, void* d_ws, size_t ws_size,
                              hipStream_t stream) {
    const float* data = (const float*)d_in[0];
    const float* crit = (const float*)d_in[1];
    const float* Wl   = (const float*)d_in[2];
    const float* bl   = (const float*)d_in[3];
    const float* Wr   = (const float*)d_in[4];
    const float* br   = (const float*)d_in[5];
    const float* agg  = (const float*)d_in[6];
    float* out  = (float*)d_out;
    ushort* ws16 = (ushort*)d_ws;   // 4 factor planes x 256x2048 bf16 = 4 MB

    // Phase 1: 32 row-tiles x 4 col-tiles x 2 K-halves x 2 sources = 512 blocks
    proj_exp_kernel<<<dim3(512), 256, 0, stream>>>(data, crit, Wl, bl, Wr, br, ws16);

    // Phase 2: (16 m-tiles x 16 n-tiles) x 4 batches = 1024 blocks; no atomics
    tanh_reduce_kernel<<<dim3(1024), 256, 0, stream>>>(ws16, agg, out);
}